// Round 1
// baseline (3584.441 us; speedup 1.0000x reference)
//
#include <hip/hip_runtime.h>

#define T_SEQ 128
#define BATCH 512

typedef _Float16 h8 __attribute__((ext_vector_type(8)));
typedef float f4 __attribute__((ext_vector_type(4)));

__device__ __forceinline__ float sigm(float x) { return 1.f / (1.f + __expf(-x)); }
__device__ __forceinline__ float tanh_fast(float x) { return 1.f - 2.f / (1.f + __expf(2.f * x)); }

// ---------------------------------------------------------------------------
// Weight pack: w_ih (f32 [G,D]) and w_hh (f32 [G,H]) -> f16, fragment-ordered
// [ntile][kc][lane][8] so each B-fragment load is one coalesced 16B/lane read.
// k in [0,DPAD) = w_ih (zero-padded), k in [DPAD,DPAD+H) = w_hh.
// Also bias = b_ih + b_hh.
// ---------------------------------------------------------------------------
__global__ void pack_kernel(const float* __restrict__ wih, const float* __restrict__ whh,
                            const float* __restrict__ bih, const float* __restrict__ bhh,
                            _Float16* __restrict__ wpack, float* __restrict__ bias,
                            int D, int H, int KC, int DPAD, int total)
{
    int s = blockIdx.x * 256 + threadIdx.x;
    int G = 4 * H;
    if (s < G) bias[s] = bih[s] + bhh[s];
    if (s >= total) return;
    int i  = s & 7;
    int l  = (s >> 3) & 63;
    int kc = (s >> 9) % KC;
    int nt = (s >> 9) / KC;
    int g  = nt * 16 + (l & 15);
    int k  = kc * 32 + ((l >> 4) << 3) + i;
    float v;
    if (k < DPAD) v = (k < D) ? wih[g * D + k] : 0.f;
    else          v = whh[g * H + (k - DPAD)];
    wpack[s] = (_Float16)v;
}

// ---------------------------------------------------------------------------
// Fused LSTM: one block owns 16 batch rows for one LSTM, loops T=128 steps.
// Per step: gates[16,4H] = [x_t | h] @ [w_ih|w_hh]^T  (mfma 16x16x32 f16,
// f32 acc) -> LDS -> cell update (f32 VALU) -> h (f16) back to LDS apack.
// apack is fragment-ordered: apack[(kc*64 + lane)*8 + i] = A[lane&15][k],
// k = kc*32 + (lane>>4)*8 + i. Same k-slot convention as wpack, so the MFMA
// dot product is invariant to the true hardware k-permutation.
// ---------------------------------------------------------------------------
template <int M>
__device__ __forceinline__ void lstm_block(int lb,
                                           const float* __restrict__ x,
                                           const _Float16* __restrict__ wpack,
                                           const float* __restrict__ bias,
                                           float* __restrict__ h_all,
                                           float* gates, _Float16* apack)
{
    constexpr int D    = (M == 0) ? 300 : (M == 1 ? 74 : 35);
    constexpr int H    = (M == 0) ? 256 : 64;
    constexpr int G    = 4 * H;
    constexpr int KCX  = (D + 31) / 32;      // 10, 3, 2
    constexpr int KC   = KCX + H / 32;       // 18, 5, 4
    constexpr int NTW  = (G / 16) / 8;       // ntiles per wave: 8, 2, 2
    constexpr int GP   = G + 4;              // gates pitch (pad vs bank conflict)
    constexpr int COLB = (M == 0) ? 0 : (M == 1 ? 256 : 320);
    constexpr int NSLOT = KCX * 64;          // x 16B-slots: 640, 192, 128
    constexpr int SPT   = (NSLOT + 511) / 512; // slots/thread: 2, 1, 1
    constexpr int UPT   = 16 * H / 8;        // update threads: 512, 128, 128

    const int tid = threadIdx.x;
    const int w = tid >> 6, l = tid & 63;
    const int r0 = lb * 16;
    const int crow = (l >> 4) * 4, ccol = l & 15; // C/D frag: row=(l>>4)*4+q, col=l&15

    f4 acc[NTW];
#pragma unroll
    for (int j = 0; j < NTW; j++) acc[j] = (f4){0.f, 0.f, 0.f, 0.f};

    // zero apack (h part must start at h0=0; x part overwritten below)
    for (int s = tid; s < KC * 64; s += 512) {
        h8 z;
#pragma unroll
        for (int i = 0; i < 8; i++) z[i] = (_Float16)0.f;
        *(h8*)&apack[s * 8] = z;
    }

    const bool upd = tid < UPT;
    const int ur  = (M == 0) ? (tid >> 5) : (tid >> 3);
    const int ujb = (M == 0) ? ((tid & 31) << 3) : ((tid & 7) << 3);
    float c[8];
#pragma unroll
    for (int i = 0; i < 8; i++) c[i] = 0.f;

    float bI[8], bF[8], bG[8], bO[8];
    if (upd) {
#pragma unroll
        for (int i = 0; i < 8; i++) {
            bI[i] = bias[ujb + i];
            bF[i] = bias[H + ujb + i];
            bG[i] = bias[2 * H + ujb + i];
            bO[i] = bias[3 * H + ujb + i];
        }
    }

    float xr[SPT * 8];

    auto issue_x = [&](int tt) {
#pragma unroll
        for (int sl = 0; sl < SPT; sl++) {
            int s = tid + sl * 512;
            if (s < NSLOT) {
                int kc = s >> 6, ls = s & 63;
                int row = ls & 15, k8 = kc * 32 + ((ls >> 4) << 3);
                const float* bp = x + ((size_t)(r0 + row) * T_SEQ + tt) * D + k8;
                if (k8 + 8 <= D) {
#pragma unroll
                    for (int i = 0; i < 8; i++) xr[sl * 8 + i] = bp[i];
                } else {
#pragma unroll
                    for (int i = 0; i < 8; i++) xr[sl * 8 + i] = (k8 + i < D) ? bp[i] : 0.f;
                }
            }
        }
    };
    auto write_x = [&]() {
#pragma unroll
        for (int sl = 0; sl < SPT; sl++) {
            int s = tid + sl * 512;
            if (s < NSLOT) {
                h8 hx;
#pragma unroll
                for (int i = 0; i < 8; i++) hx[i] = (_Float16)xr[sl * 8 + i];
                *(h8*)&apack[s * 8] = hx;
            }
        }
    };

    // prologue: x for t=0
    issue_x(0);
    write_x();
    __syncthreads();

    const h8* wp8 = (const h8*)wpack;

    for (int t = 0; t < T_SEQ; t++) {
        if (t + 1 < T_SEQ) issue_x(t + 1); // loads in flight during MFMA phase

        // phase A: gates GEMM
        for (int kc = 0; kc < KC; kc++) {
            h8 a = *(const h8*)&apack[(kc * 64 + l) * 8];
#pragma unroll
            for (int j = 0; j < NTW; j++) {
                h8 b = wp8[((w * NTW + j) * KC + kc) * 64 + l];
                acc[j] = __builtin_amdgcn_mfma_f32_16x16x32_f16(a, b, acc[j], 0, 0, 0);
            }
        }

        // phase B: acc -> gates LDS, re-zero acc
#pragma unroll
        for (int j = 0; j < NTW; j++) {
#pragma unroll
            for (int q = 0; q < 4; q++)
                gates[(crow + q) * GP + (w * NTW + j) * 16 + ccol] = acc[j][q];
            acc[j] = (f4){0.f, 0.f, 0.f, 0.f};
        }
        __syncthreads();

        // phase C: cell update
        if (upd) {
            const int gb = ur * GP + ujb;
            f4 vI[2], vF[2], vG[2], vO[2];
            vI[0] = *(const f4*)&gates[gb];             vI[1] = *(const f4*)&gates[gb + 4];
            vF[0] = *(const f4*)&gates[gb + H];         vF[1] = *(const f4*)&gates[gb + H + 4];
            vG[0] = *(const f4*)&gates[gb + 2 * H];     vG[1] = *(const f4*)&gates[gb + 2 * H + 4];
            vO[0] = *(const f4*)&gates[gb + 3 * H];     vO[1] = *(const f4*)&gates[gb + 3 * H + 4];
            float hv[8];
#pragma unroll
            for (int i = 0; i < 8; i++) {
                float gi = ((i < 4) ? vI[0][i & 3] : vI[1][i & 3]) + bI[i];
                float gf = ((i < 4) ? vF[0][i & 3] : vF[1][i & 3]) + bF[i];
                float gg = ((i < 4) ? vG[0][i & 3] : vG[1][i & 3]) + bG[i];
                float go = ((i < 4) ? vO[0][i & 3] : vO[1][i & 3]) + bO[i];
                float cn = sigm(gf) * c[i] + sigm(gi) * tanh_fast(gg);
                c[i] = cn;
                hv[i] = sigm(go) * tanh_fast(cn);
            }
            if (t == T_SEQ - 1) {
#pragma unroll
                for (int i = 0; i < 8; i++)
                    h_all[(size_t)(r0 + ur) * 384 + COLB + ujb + i] = hv[i];
            } else {
                h8 hh;
#pragma unroll
                for (int i = 0; i < 8; i++) hh[i] = (_Float16)hv[i];
                // h element (r=ur, j) -> k = DPAD + j: kc = KCX + (j>>5),
                // lane = ((j&31)>>3)*16 + r, i = j&7
                *(h8*)&apack[((KCX + (ujb >> 5)) * 64 + (((ujb & 31) >> 3) << 4) + ur) * 8] = hh;
            }
        }
        if (t + 1 < T_SEQ) write_x();
        __syncthreads();
    }
}

__global__ __launch_bounds__(512) void lstm_kernel(
    const float* __restrict__ x0, const float* __restrict__ x1, const float* __restrict__ x2,
    const _Float16* __restrict__ wp0, const _Float16* __restrict__ wp1, const _Float16* __restrict__ wp2,
    const float* __restrict__ bs0, const float* __restrict__ bs1, const float* __restrict__ bs2,
    float* __restrict__ h_all)
{
    __shared__ float    gates[16 * 1028];   // 65,792 B (LSTM0 pitch 1028)
    __shared__ _Float16 apack[18 * 512];    // 18,432 B (LSTM0: 18 k-chunks)
    int bid = blockIdx.x;
    if (bid < 32)       lstm_block<0>(bid,      x0, wp0, bs0, h_all, gates, apack);
    else if (bid < 64)  lstm_block<1>(bid - 32, x1, wp1, bs1, h_all, gates, apack);
    else                lstm_block<2>(bid - 64, x2, wp2, bs2, h_all, gates, apack);
}

// ---------------------------------------------------------------------------
// MLP head: out[r] = w2 . relu(w1 @ h_all[r] + b1) + b2. 64 blocks x 8 waves,
// one row per wave, one hid-column per lane (H_OUT = 64 = wave size).
// ---------------------------------------------------------------------------
__global__ __launch_bounds__(512) void mlp_kernel(const float* __restrict__ h_all,
                                                  const float* __restrict__ w1,
                                                  const float* __restrict__ b1,
                                                  const float* __restrict__ w2,
                                                  const float* __restrict__ b2,
                                                  float* __restrict__ out)
{
    __shared__ float w1s[64 * 385]; // pitch 385: stride%32==1 -> conflict-free
    __shared__ float hs[8 * 384];
    int tid = threadIdx.x;
    for (int idx = tid; idx < 64 * 384; idx += 512) {
        int j = idx / 384, k = idx - j * 384;
        w1s[j * 385 + k] = w1[idx];
    }
    int r0 = blockIdx.x * 8;
    for (int idx = tid; idx < 8 * 384; idx += 512) hs[idx] = h_all[(size_t)r0 * 384 + idx];
    __syncthreads();

    int w = tid >> 6, j = tid & 63;
    float accv = b1[j];
    const float* hrow = &hs[w * 384];
    for (int k = 0; k < 384; k++) accv = fmaf(hrow[k], w1s[j * 385 + k], accv);
    float hid = fmaxf(accv, 0.f);
    float v = hid * w2[j];
#pragma unroll
    for (int off = 32; off >= 1; off >>= 1) v += __shfl_xor(v, off, 64);
    if (j == 0) out[r0 + w] = v + b2[0];
}

// ---------------------------------------------------------------------------
extern "C" void kernel_launch(void* const* d_in, const int* in_sizes, int n_in,
                              void* d_out, int out_size, void* d_ws, size_t ws_size,
                              hipStream_t stream)
{
    const float* x0   = (const float*)d_in[0];
    const float* x1   = (const float*)d_in[1];
    const float* x2   = (const float*)d_in[2];
    const float* wih0 = (const float*)d_in[3];
    const float* whh0 = (const float*)d_in[4];
    const float* bih0 = (const float*)d_in[5];
    const float* bhh0 = (const float*)d_in[6];
    const float* wih1 = (const float*)d_in[7];
    const float* whh1 = (const float*)d_in[8];
    const float* bih1 = (const float*)d_in[9];
    const float* bhh1 = (const float*)d_in[10];
    const float* wih2 = (const float*)d_in[11];
    const float* whh2 = (const float*)d_in[12];
    const float* bih2 = (const float*)d_in[13];
    const float* bhh2 = (const float*)d_in[14];
    const float* w1   = (const float*)d_in[15];
    const float* b1   = (const float*)d_in[16];
    const float* w2   = (const float*)d_in[17];
    const float* b2   = (const float*)d_in[18];

    char* ws = (char*)d_ws;
    // ws layout (bytes): wp0 1,179,648 | wp1 81,920 | wp2 65,536 |
    //                    bias0 4,096 | bias1 1,024 | bias2 1,024 | h_all 786,432
    _Float16* wp0   = (_Float16*)(ws);
    _Float16* wp1   = (_Float16*)(ws + 1179648);
    _Float16* wp2   = (_Float16*)(ws + 1179648 + 81920);
    float*    bias0 = (float*)(ws + 1327104);
    float*    bias1 = (float*)(ws + 1331200);
    float*    bias2 = (float*)(ws + 1332224);
    float*    h_all = (float*)(ws + 1333248);

    // pack: total slots = NT*KC*512
    pack_kernel<<<(589824 + 255) / 256, 256, 0, stream>>>(wih0, whh0, bih0, bhh0, wp0, bias0,
                                                          300, 256, 18, 320, 589824);
    pack_kernel<<<(40960 + 255) / 256, 256, 0, stream>>>(wih1, whh1, bih1, bhh1, wp1, bias1,
                                                         74, 64, 5, 96, 40960);
    pack_kernel<<<(32768 + 255) / 256, 256, 0, stream>>>(wih2, whh2, bih2, bhh2, wp2, bias2,
                                                         35, 64, 4, 64, 32768);

    lstm_kernel<<<96, 512, 0, stream>>>(x0, x1, x2, wp0, wp1, wp2, bias0, bias1, bias2, h_all);

    mlp_kernel<<<64, 512, 0, stream>>>(h_all, w1, b1, w2, b2, (float*)d_out);
}

// Round 2
// 2344.731 us; speedup vs baseline: 1.5287x; 1.5287x over previous
//
#include <hip/hip_runtime.h>

typedef _Float16 h8 __attribute__((ext_vector_type(8)));
typedef float f4 __attribute__((ext_vector_type(4)));
typedef unsigned int u32x4 __attribute__((ext_vector_type(4)));

__device__ __forceinline__ float sigm(float x) { return 1.f / (1.f + __expf(-x)); }
__device__ __forceinline__ float tanhf_(float x) { return 1.f - 2.f / (1.f + __expf(2.f * x)); }

// ---------------------------------------------------------------------------
// pack_all: all six weight matrices -> f16 fragment layout [gt][kc][lane][8],
// value(gt,kc,lane,i) = W[gt*16 + (lane&15)][kc*32 + ((lane>>4)<<3) + i] (0-pad).
// Plus combined biases (b_ih+b_hh) as f32.
// Slot ranges: wihp0 40960 | whhp0 32768 | wihp1 3072 | whhp1 2048 |
//              wihp2 2048 | whhp2 2048  (total 82944 = 324 blocks)
// ---------------------------------------------------------------------------
__global__ __launch_bounds__(256) void pack_all(
    const float* __restrict__ wih0, const float* __restrict__ whh0,
    const float* __restrict__ wih1, const float* __restrict__ whh1,
    const float* __restrict__ wih2, const float* __restrict__ whh2,
    const float* __restrict__ bih0, const float* __restrict__ bhh0,
    const float* __restrict__ bih1, const float* __restrict__ bhh1,
    const float* __restrict__ bih2, const float* __restrict__ bhh2,
    _Float16* __restrict__ wihp0, _Float16* __restrict__ whhp0,
    _Float16* __restrict__ wihp1, _Float16* __restrict__ whhp1,
    _Float16* __restrict__ wihp2, _Float16* __restrict__ whhp2,
    float* __restrict__ biasc)
{
    if (blockIdx.x >= 324) {
        int bi = (blockIdx.x - 324) * 256 + threadIdx.x;
        if (bi < 1024)      biasc[bi] = bih0[bi] + bhh0[bi];
        else if (bi < 1280) biasc[bi] = bih1[bi - 1024] + bhh1[bi - 1024];
        else if (bi < 1536) biasc[bi] = bih2[bi - 1280] + bhh2[bi - 1280];
        return;
    }
    int s = blockIdx.x * 256 + threadIdx.x;
    const float* src; _Float16* dst; int KC, D;
    if (s < 40960)      {            dst = wihp0; src = wih0; KC = 10; D = 300; }
    else if (s < 73728) { s -= 40960; dst = whhp0; src = whh0; KC = 8;  D = 256; }
    else if (s < 76800) { s -= 73728; dst = wihp1; src = wih1; KC = 3;  D = 74;  }
    else if (s < 78848) { s -= 76800; dst = whhp1; src = whh1; KC = 2;  D = 64;  }
    else if (s < 80896) { s -= 78848; dst = wihp2; src = wih2; KC = 2;  D = 35;  }
    else                { s -= 80896; dst = whhp2; src = whh2; KC = 2;  D = 64;  }
    int lane = s & 63;
    int kc = (s >> 6) % KC;
    int gt = (s >> 6) / KC;
    int g = gt * 16 + (lane & 15);
    int kb = kc * 32 + ((lane >> 4) << 3);
    h8 v;
#pragma unroll
    for (int i = 0; i < 8; i++) {
        int k = kb + i;
        v[i] = (_Float16)((k < D) ? src[(size_t)g * D + k] : 0.f);
    }
    *(h8*)&dst[(size_t)s * 8] = v;
}

// ---------------------------------------------------------------------------
// xg phase: xg = x @ w_ih^T + (b_ih+b_hh), f16, stored pre-packed in the
// recurrence fragment layout:
//   LSTM0: [tc][bb(16)][w(8)][fp(8)][lane(64)][16B]   (bb = 32-row group)
//   LSTM1/2: [tc][bb(8)][w(8)][fp(4)][lane(64)][16B]  (bb = 64-row group)
// fp-pair 16B = [gate(2gp) q0..3 | gate(2gp+1) q0..3] as f16.
// ---------------------------------------------------------------------------
template <int M>
__device__ __forceinline__ void xg_block(int tc, int bq, int t0,
    const float* __restrict__ x, const _Float16* __restrict__ wihp,
    const float* __restrict__ bias, _Float16* __restrict__ xgp, _Float16* axf)
{
    constexpr int D   = (M == 0) ? 300 : ((M == 1) ? 74 : 35);
    constexpr int KCX = (M == 0) ? 10 : ((M == 1) ? 3 : 2);
    const int t = t0 + tc;
    const int tid = threadIdx.x, w = tid >> 6, l = tid & 63, ccol = l & 15;
    const int r0 = bq * 64;

    // stage A tile (64 rows x KCX*32 k) as f16 frags in LDS
    for (int s = tid; s < 4 * KCX * 64; s += 512) {
        int rt = s / (KCX * 64);
        int kc = (s >> 6) % KCX;
        int ll = s & 63;
        int row = r0 + rt * 16 + (ll & 15);
        int kb = kc * 32 + ((ll >> 4) << 3);
        const float* bp = x + ((size_t)row * 128 + t) * D + kb;
        h8 v;
#pragma unroll
        for (int i = 0; i < 8; i++) v[i] = (_Float16)((kb + i < D) ? bp[i] : 0.f);
        *(h8*)&axf[s * 8] = v;
    }
    __syncthreads();

    if (M == 0) {
        f4 acc[4][8];
#pragma unroll
        for (int g = 0; g < 8; g++) {
            int gt = (g >> 1) * 16 + 2 * w + (g & 1);
            float b = bias[gt * 16 + ccol];
#pragma unroll
            for (int rt = 0; rt < 4; rt++) acc[rt][g] = (f4){b, b, b, b};
        }
#pragma unroll
        for (int kc = 0; kc < KCX; kc++) {
            h8 a[4];
#pragma unroll
            for (int rt = 0; rt < 4; rt++) a[rt] = *(const h8*)&axf[((rt * KCX + kc) * 64 + l) * 8];
#pragma unroll
            for (int g = 0; g < 8; g++) {
                int gt = (g >> 1) * 16 + 2 * w + (g & 1);
                h8 b = *(const h8*)&wihp[((size_t)(gt * KCX + kc) * 64 + l) * 8];
#pragma unroll
                for (int rt = 0; rt < 4; rt++)
                    acc[rt][g] = __builtin_amdgcn_mfma_f32_16x16x32_f16(a[rt], b, acc[rt][g], 0, 0, 0);
            }
        }
#pragma unroll
        for (int rt = 0; rt < 4; rt++) {
            int bb = bq * 2 + (rt >> 1), rtl = rt & 1;
#pragma unroll
            for (int jt = 0; jt < 2; jt++)
#pragma unroll
            for (int gp = 0; gp < 2; gp++) {
                f4 lo = acc[rt][(2 * gp) * 2 + jt], hi = acc[rt][(2 * gp + 1) * 2 + jt];
                h8 v;
#pragma unroll
                for (int q = 0; q < 4; q++) { v[q] = (_Float16)lo[q]; v[4 + q] = (_Float16)hi[q]; }
                int fp = (rtl * 2 + jt) * 2 + gp;
                size_t off = ((((size_t)tc * 16 + bb) * 8 + w) * 8 + fp) * 64 + l;
                *(h8*)&xgp[off * 8] = v;
            }
        }
    } else {
        const int rh = w >> 2, ht = w & 3;
        f4 acc[2][4];
#pragma unroll
        for (int ga = 0; ga < 4; ga++) {
            int gt = ga * 4 + ht;
            float b = bias[gt * 16 + ccol];
            acc[0][ga] = (f4){b, b, b, b};
            acc[1][ga] = (f4){b, b, b, b};
        }
#pragma unroll
        for (int kc = 0; kc < KCX; kc++) {
            h8 a[2];
#pragma unroll
            for (int rr = 0; rr < 2; rr++)
                a[rr] = *(const h8*)&axf[(((rh * 2 + rr) * KCX + kc) * 64 + l) * 8];
#pragma unroll
            for (int ga = 0; ga < 4; ga++) {
                int gt = ga * 4 + ht;
                h8 b = *(const h8*)&wihp[((size_t)(gt * KCX + kc) * 64 + l) * 8];
#pragma unroll
                for (int rr = 0; rr < 2; rr++)
                    acc[rr][ga] = __builtin_amdgcn_mfma_f32_16x16x32_f16(a[rr], b, acc[rr][ga], 0, 0, 0);
            }
        }
#pragma unroll
        for (int rr = 0; rr < 2; rr++)
#pragma unroll
        for (int gp = 0; gp < 2; gp++) {
            f4 lo = acc[rr][2 * gp], hi = acc[rr][2 * gp + 1];
            h8 v;
#pragma unroll
            for (int q = 0; q < 4; q++) { v[q] = (_Float16)lo[q]; v[4 + q] = (_Float16)hi[q]; }
            int fp = rr * 2 + gp;
            size_t off = ((((size_t)tc * 8 + bq) * 8 + w) * 4 + fp) * 64 + l;
            *(h8*)&xgp[off * 8] = v;
        }
    }
}

__global__ __launch_bounds__(512, 2) void xg_kernel(
    const float* __restrict__ x0, const float* __restrict__ x1, const float* __restrict__ x2,
    const _Float16* __restrict__ wihp0, const _Float16* __restrict__ wihp1,
    const _Float16* __restrict__ wihp2, const float* __restrict__ biasc,
    _Float16* __restrict__ xgp0, _Float16* __restrict__ xgp1, _Float16* __restrict__ xgp2,
    int t0, int TC)
{
    __shared__ __align__(16) _Float16 axf[4 * 10 * 64 * 8];
    int b = blockIdx.x;
    int per = TC * 8;
    if (b < per)            xg_block<0>(b >> 3, b & 7, t0, x0, wihp0, biasc,        xgp0, axf);
    else if (b < 2 * per) { b -= per;     xg_block<1>(b >> 3, b & 7, t0, x1, wihp1, biasc + 1024, xgp1, axf); }
    else                  { b -= 2 * per; xg_block<2>(b >> 3, b & 7, t0, x2, wihp2, biasc + 1280, xgp2, axf); }
}

// ---------------------------------------------------------------------------
// Recurrence: grid=32. Blocks 0-15: LSTM0 (32 rows each, w_hh streamed from
// L2, 512KB/step). Blocks 16-23 / 24-31: LSTM1/2 (64 rows each, w_hh in LDS).
// gates = xg_t (acc-init, bias folded) + h @ w_hh^T; cell update in-register;
// h -> LDS apack (double-buffered, fragment layout); c stays in VGPRs.
// Chunked over t via csave/hsave in ws.
// ---------------------------------------------------------------------------
__global__ __launch_bounds__(512, 2) void rec_kernel(
    const _Float16* __restrict__ whhp0, const _Float16* __restrict__ whhp1,
    const _Float16* __restrict__ whhp2,
    const _Float16* __restrict__ xgp0, const _Float16* __restrict__ xgp1,
    const _Float16* __restrict__ xgp2,
    float* __restrict__ h_all, float* __restrict__ csave, _Float16* __restrict__ hsave,
    int t0, int TC)
{
    __shared__ __align__(16) char smem[49152];
    const int bid = blockIdx.x;
    const int tid = threadIdx.x, w = tid >> 6, l = tid & 63;
    const int ccol = l & 15, crow = (l >> 4) * 4;
    float* cs = csave + ((size_t)bid * 512 + tid) * 16;

    if (bid < 16) {
        // ----- LSTM0 -----
        _Float16* apkA = (_Float16*)smem;            // 16 KB
        _Float16* apkB = (_Float16*)(smem + 16384);  // 16 KB
        const int lb = bid, r0 = lb * 32;
        float c[16];
        h8 xbuf[8];
        if (t0 == 0) {
#pragma unroll
            for (int i = 0; i < 16; i++) c[i] = 0.f;
            u32x4 z = (u32x4){0u, 0u, 0u, 0u};
            for (int s = tid; s < 1024; s += 512) ((u32x4*)apkA)[s] = z;
        } else {
#pragma unroll
            for (int i = 0; i < 16; i++) c[i] = cs[i];
            const u32x4* hsrc = (const u32x4*)(hsave + (size_t)lb * 8192);
            for (int s = tid; s < 1024; s += 512) ((u32x4*)apkA)[s] = hsrc[s];
        }
        __syncthreads();

        const size_t xbase = ((size_t)lb * 8 + w) * 8 * 512 + (size_t)l * 8;
#pragma unroll
        for (int fp = 0; fp < 8; fp++)
            xbuf[fp] = *(const h8*)&xgp0[xbase + (size_t)fp * 512];

        f4 acc[2][8];
        for (int tc = 0; tc < TC; tc++) {
            _Float16* cur = (tc & 1) ? apkB : apkA;
            _Float16* nxt = (tc & 1) ? apkA : apkB;
            // acc init from xg frags
#pragma unroll
            for (int rt = 0; rt < 2; rt++)
#pragma unroll
            for (int jt = 0; jt < 2; jt++)
#pragma unroll
            for (int gp = 0; gp < 2; gp++) {
                int fp = (rt * 2 + jt) * 2 + gp;
#pragma unroll
                for (int q = 0; q < 4; q++) {
                    acc[rt][(2 * gp) * 2 + jt][q]     = (float)xbuf[fp][q];
                    acc[rt][(2 * gp + 1) * 2 + jt][q] = (float)xbuf[fp][4 + q];
                }
            }
            if (tc + 1 < TC) {
                size_t nb = xbase + (size_t)(tc + 1) * 16 * 8 * 8 * 512;
#pragma unroll
                for (int fp = 0; fp < 8; fp++)
                    xbuf[fp] = *(const h8*)&xgp0[nb + (size_t)fp * 512];
            }
            // gates += h @ w_hh^T
#pragma unroll
            for (int kc = 0; kc < 8; kc++) {
                h8 a0 = *(const h8*)&cur[((0 * 8 + kc) * 64 + l) * 8];
                h8 a1 = *(const h8*)&cur[((1 * 8 + kc) * 64 + l) * 8];
#pragma unroll
                for (int g = 0; g < 8; g++) {
                    int gt = (g >> 1) * 16 + 2 * w + (g & 1);
                    h8 b = *(const h8*)&whhp0[((size_t)(gt * 8 + kc) * 64 + l) * 8];
                    acc[0][g] = __builtin_amdgcn_mfma_f32_16x16x32_f16(a0, b, acc[0][g], 0, 0, 0);
                    acc[1][g] = __builtin_amdgcn_mfma_f32_16x16x32_f16(a1, b, acc[1][g], 0, 0, 0);
                }
            }
            // cell update (in-register)
            const int t = t0 + tc;
#pragma unroll
            for (int rt = 0; rt < 2; rt++)
#pragma unroll
            for (int jt = 0; jt < 2; jt++)
#pragma unroll
            for (int q = 0; q < 4; q++) {
                int idx = rt * 8 + jt * 4 + q;
                float gi = acc[rt][0 + jt][q];
                float gf = acc[rt][2 + jt][q];
                float gg = acc[rt][4 + jt][q];
                float go = acc[rt][6 + jt][q];
                float cn = sigm(gf) * c[idx] + sigm(gi) * tanhf_(gg);
                c[idx] = cn;
                float hv = sigm(go) * tanhf_(cn);
                int row = rt * 16 + crow + q;
                int hcol = w * 32 + jt * 16 + ccol;
                if (t == 127) h_all[(size_t)(r0 + row) * 384 + hcol] = hv;
                int sub = jt * 2 + (ccol >> 3);
                nxt[((rt * 8 + w) * 64 + sub * 16 + (row & 15)) * 8 + (ccol & 7)] = (_Float16)hv;
            }
            __syncthreads();
        }
        if (t0 + TC < 128) {
#pragma unroll
            for (int i = 0; i < 16; i++) cs[i] = c[i];
            u32x4* hdst = (u32x4*)(hsave + (size_t)lb * 8192);
            const u32x4* src = (const u32x4*)((TC & 1) ? apkB : apkA);
            for (int s = tid; s < 1024; s += 512) hdst[s] = src[s];
        }
    } else {
        // ----- LSTM1 / LSTM2 -----
        const int m = (bid < 24) ? 1 : 2;
        const int lb = (bid - 16) & 7;
        const int r0 = lb * 64;
        const int colb = (m == 1) ? 256 : 320;
        const _Float16* whhp = (m == 1) ? whhp1 : whhp2;
        const _Float16* xgp  = (m == 1) ? xgp1 : xgp2;
        _Float16* whhs = (_Float16*)smem;                 // 32 KB
        _Float16* apkA = (_Float16*)(smem + 32768);       // 8 KB
        _Float16* apkB = (_Float16*)(smem + 40960);       // 8 KB
        const int rh = w >> 2, ht = w & 3;
        float c[8];
        h8 xbuf[4];
        for (int s = tid; s < 2048; s += 512) ((u32x4*)whhs)[s] = ((const u32x4*)whhp)[s];
        if (t0 == 0) {
#pragma unroll
            for (int i = 0; i < 8; i++) c[i] = 0.f;
            u32x4 z = (u32x4){0u, 0u, 0u, 0u};
            for (int s = tid; s < 512; s += 512) ((u32x4*)apkA)[s] = z;
        } else {
#pragma unroll
            for (int i = 0; i < 8; i++) c[i] = cs[i];
            const u32x4* hsrc = (const u32x4*)(hsave + 16 * 8192 + (size_t)(bid - 16) * 4096);
            for (int s = tid; s < 512; s += 512) ((u32x4*)apkA)[s] = hsrc[s];
        }
        __syncthreads();

        const size_t xbase = ((size_t)lb * 8 + w) * 4 * 512 + (size_t)l * 8;
#pragma unroll
        for (int fp = 0; fp < 4; fp++)
            xbuf[fp] = *(const h8*)&xgp[xbase + (size_t)fp * 512];

        f4 acc[2][4];
        for (int tc = 0; tc < TC; tc++) {
            _Float16* cur = (tc & 1) ? apkB : apkA;
            _Float16* nxt = (tc & 1) ? apkA : apkB;
#pragma unroll
            for (int rr = 0; rr < 2; rr++)
#pragma unroll
            for (int gp = 0; gp < 2; gp++) {
                int fp = rr * 2 + gp;
#pragma unroll
                for (int q = 0; q < 4; q++) {
                    acc[rr][2 * gp][q]     = (float)xbuf[fp][q];
                    acc[rr][2 * gp + 1][q] = (float)xbuf[fp][4 + q];
                }
            }
            if (tc + 1 < TC) {
                size_t nb = xbase + (size_t)(tc + 1) * 8 * 8 * 4 * 512;
#pragma unroll
                for (int fp = 0; fp < 4; fp++)
                    xbuf[fp] = *(const h8*)&xgp[nb + (size_t)fp * 512];
            }
#pragma unroll
            for (int kc = 0; kc < 2; kc++) {
                h8 a0 = *(const h8*)&cur[(((rh * 2 + 0) * 2 + kc) * 64 + l) * 8];
                h8 a1 = *(const h8*)&cur[(((rh * 2 + 1) * 2 + kc) * 64 + l) * 8];
#pragma unroll
                for (int ga = 0; ga < 4; ga++) {
                    int gt = ga * 4 + ht;
                    h8 b = *(const h8*)&whhs[((gt * 2 + kc) * 64 + l) * 8];
                    acc[0][ga] = __builtin_amdgcn_mfma_f32_16x16x32_f16(a0, b, acc[0][ga], 0, 0, 0);
                    acc[1][ga] = __builtin_amdgcn_mfma_f32_16x16x32_f16(a1, b, acc[1][ga], 0, 0, 0);
                }
            }
            const int t = t0 + tc;
#pragma unroll
            for (int rr = 0; rr < 2; rr++)
#pragma unroll
            for (int q = 0; q < 4; q++) {
                int idx = rr * 4 + q;
                float gi = acc[rr][0][q];
                float gf = acc[rr][1][q];
                float gg = acc[rr][2][q];
                float go = acc[rr][3][q];
                float cn = sigm(gf) * c[idx] + sigm(gi) * tanhf_(gg);
                c[idx] = cn;
                float hv = sigm(go) * tanhf_(cn);
                int row = (rh * 2 + rr) * 16 + crow + q;
                int hcol = ht * 16 + ccol;
                if (t == 127) h_all[(size_t)(r0 + row) * 384 + colb + hcol] = hv;
                int kch = ht >> 1;
                int sub = (ht & 1) * 2 + (ccol >> 3);
                nxt[(((row >> 4) * 2 + kch) * 64 + sub * 16 + (row & 15)) * 8 + (ccol & 7)] = (_Float16)hv;
            }
            __syncthreads();
        }
        if (t0 + TC < 128) {
#pragma unroll
            for (int i = 0; i < 8; i++) cs[i] = c[i];
            u32x4* hdst = (u32x4*)(hsave + 16 * 8192 + (size_t)(bid - 16) * 4096);
            const u32x4* src = (const u32x4*)((TC & 1) ? apkB : apkA);
            for (int s = tid; s < 512; s += 512) hdst[s] = src[s];
        }
    }
}

// ---------------------------------------------------------------------------
// MLP head (unchanged from round 1 — verified)
// ---------------------------------------------------------------------------
__global__ __launch_bounds__(512) void mlp_kernel(const float* __restrict__ h_all,
                                                  const float* __restrict__ w1,
                                                  const float* __restrict__ b1,
                                                  const float* __restrict__ w2,
                                                  const float* __restrict__ b2,
                                                  float* __restrict__ out)
{
    __shared__ float w1s[64 * 385];
    __shared__ float hs[8 * 384];
    int tid = threadIdx.x;
    for (int idx = tid; idx < 64 * 384; idx += 512) {
        int j = idx / 384, k = idx - j * 384;
        w1s[j * 385 + k] = w1[idx];
    }
    int r0 = blockIdx.x * 8;
    for (int idx = tid; idx < 8 * 384; idx += 512) hs[idx] = h_all[(size_t)r0 * 384 + idx];
    __syncthreads();

    int w = tid >> 6, j = tid & 63;
    float accv = b1[j];
    const float* hrow = &hs[w * 384];
    for (int k = 0; k < 384; k++) accv = fmaf(hrow[k], w1s[j * 385 + k], accv);
    float hid = fmaxf(accv, 0.f);
    float v = hid * w2[j];
#pragma unroll
    for (int off = 32; off >= 1; off >>= 1) v += __shfl_xor(v, off, 64);
    if (j == 0) out[r0 + w] = v + b2[0];
}

// ---------------------------------------------------------------------------
extern "C" void kernel_launch(void* const* d_in, const int* in_sizes, int n_in,
                              void* d_out, int out_size, void* d_ws, size_t ws_size,
                              hipStream_t stream)
{
    const float* x0   = (const float*)d_in[0];
    const float* x1   = (const float*)d_in[1];
    const float* x2   = (const float*)d_in[2];
    const float* wih0 = (const float*)d_in[3];
    const float* whh0 = (const float*)d_in[4];
    const float* bih0 = (const float*)d_in[5];
    const float* bhh0 = (const float*)d_in[6];
    const float* wih1 = (const float*)d_in[7];
    const float* whh1 = (const float*)d_in[8];
    const float* bih1 = (const float*)d_in[9];
    const float* bhh1 = (const float*)d_in[10];
    const float* wih2 = (const float*)d_in[11];
    const float* whh2 = (const float*)d_in[12];
    const float* bih2 = (const float*)d_in[13];
    const float* bhh2 = (const float*)d_in[14];
    const float* w1   = (const float*)d_in[15];
    const float* b1   = (const float*)d_in[16];
    const float* w2   = (const float*)d_in[17];
    const float* b2   = (const float*)d_in[18];

    char* ws = (char*)d_ws;
    size_t off = 0;
    auto alloc = [&](size_t bytes) { size_t o = off; off = (off + bytes + 255) & ~255ULL; return o; };
    size_t o_wihp0 = alloc(655360);
    size_t o_whhp0 = alloc(524288);
    size_t o_wihp1 = alloc(49152);
    size_t o_whhp1 = alloc(32768);
    size_t o_wihp2 = alloc(32768);
    size_t o_whhp2 = alloc(32768);
    size_t o_bias  = alloc(6144);
    size_t o_hall  = alloc(786432);
    size_t o_csave = alloc(1048576);
    size_t o_hsave = alloc(393216);
    size_t fixed = off;

    int TC = 128;
    while (TC > 1 && fixed + (size_t)TC * 1572864ULL + 1024 > ws_size) TC >>= 1;
    size_t o_xgp0 = alloc((size_t)TC * 1048576ULL);
    size_t o_xgp1 = alloc((size_t)TC * 262144ULL);
    size_t o_xgp2 = alloc((size_t)TC * 262144ULL);

    _Float16* wihp0 = (_Float16*)(ws + o_wihp0);
    _Float16* whhp0 = (_Float16*)(ws + o_whhp0);
    _Float16* wihp1 = (_Float16*)(ws + o_wihp1);
    _Float16* whhp1 = (_Float16*)(ws + o_whhp1);
    _Float16* wihp2 = (_Float16*)(ws + o_wihp2);
    _Float16* whhp2 = (_Float16*)(ws + o_whhp2);
    float*    biasc = (float*)(ws + o_bias);
    float*    hall  = (float*)(ws + o_hall);
    float*    csave = (float*)(ws + o_csave);
    _Float16* hsave = (_Float16*)(ws + o_hsave);
    _Float16* xgp0  = (_Float16*)(ws + o_xgp0);
    _Float16* xgp1  = (_Float16*)(ws + o_xgp1);
    _Float16* xgp2  = (_Float16*)(ws + o_xgp2);

    pack_all<<<330, 256, 0, stream>>>(wih0, whh0, wih1, whh1, wih2, whh2,
                                      bih0, bhh0, bih1, bhh1, bih2, bhh2,
                                      wihp0, whhp0, wihp1, whhp1, wihp2, whhp2, biasc);

    for (int t0 = 0; t0 < 128; t0 += TC) {
        xg_kernel<<<24 * TC, 512, 0, stream>>>(x0, x1, x2, wihp0, wihp1, wihp2, biasc,
                                               xgp0, xgp1, xgp2, t0, TC);
        rec_kernel<<<32, 512, 0, stream>>>(whhp0, whhp1, whhp2, xgp0, xgp1, xgp2,
                                           hall, csave, hsave, t0, TC);
    }

    mlp_kernel<<<64, 512, 0, stream>>>(hall, w1, b1, w2, b2, (float*)d_out);
}

// Round 3
// 645.068 us; speedup vs baseline: 5.5567x; 3.6349x over previous
//
#include <hip/hip_runtime.h>

typedef _Float16 h8 __attribute__((ext_vector_type(8)));
typedef _Float16 h4 __attribute__((ext_vector_type(4)));
typedef float f4 __attribute__((ext_vector_type(4)));
typedef unsigned int u32x4 __attribute__((ext_vector_type(4)));
typedef unsigned long long u64;

__device__ __forceinline__ float sigm(float x) { return 1.f / (1.f + __expf(-x)); }
__device__ __forceinline__ float tanhf_(float x) { return 1.f - 2.f / (1.f + __expf(2.f * x)); }

// ---------------------------------------------------------------------------
// pack_all: weights -> f16 fragment layout [gt][kc][lane][8],
// value(gt,kc,lane,i) = W[gt*16 + (lane&15)][kc*32 + ((lane>>4)<<3) + i] (0-pad).
// biasc = b_ih + b_hh (f32).
// ---------------------------------------------------------------------------
__global__ __launch_bounds__(256) void pack_all(
    const float* __restrict__ wih0, const float* __restrict__ whh0,
    const float* __restrict__ wih1, const float* __restrict__ whh1,
    const float* __restrict__ wih2, const float* __restrict__ whh2,
    const float* __restrict__ bih0, const float* __restrict__ bhh0,
    const float* __restrict__ bih1, const float* __restrict__ bhh1,
    const float* __restrict__ bih2, const float* __restrict__ bhh2,
    _Float16* __restrict__ wihp0, _Float16* __restrict__ whhp0,
    _Float16* __restrict__ wihp1, _Float16* __restrict__ whhp1,
    _Float16* __restrict__ wihp2, _Float16* __restrict__ whhp2,
    float* __restrict__ biasc)
{
    if (blockIdx.x >= 324) {
        int bi = (blockIdx.x - 324) * 256 + threadIdx.x;
        if (bi < 1024)      biasc[bi] = bih0[bi] + bhh0[bi];
        else if (bi < 1280) biasc[bi] = bih1[bi - 1024] + bhh1[bi - 1024];
        else if (bi < 1536) biasc[bi] = bih2[bi - 1280] + bhh2[bi - 1280];
        return;
    }
    int s = blockIdx.x * 256 + threadIdx.x;
    const float* src; _Float16* dst; int KC, D;
    if (s < 40960)      {            dst = wihp0; src = wih0; KC = 10; D = 300; }
    else if (s < 73728) { s -= 40960; dst = whhp0; src = whh0; KC = 8;  D = 256; }
    else if (s < 76800) { s -= 73728; dst = wihp1; src = wih1; KC = 3;  D = 74;  }
    else if (s < 78848) { s -= 76800; dst = whhp1; src = whh1; KC = 2;  D = 64;  }
    else if (s < 80896) { s -= 78848; dst = wihp2; src = wih2; KC = 2;  D = 35;  }
    else                { s -= 80896; dst = whhp2; src = whh2; KC = 2;  D = 64;  }
    int lane = s & 63;
    int kc = (s >> 6) % KC;
    int gt = (s >> 6) / KC;
    int g = gt * 16 + (lane & 15);
    int kb = kc * 32 + ((lane >> 4) << 3);
    h8 v;
#pragma unroll
    for (int i = 0; i < 8; i++) {
        int k = kb + i;
        v[i] = (_Float16)((k < D) ? src[(size_t)g * D + k] : 0.f);
    }
    *(h8*)&dst[(size_t)s * 8] = v;
}

// ---------------------------------------------------------------------------
// xg phase: xg = x @ w_ih^T + bias (f16), pre-packed for the recurrence.
// LSTM0 layout: [tc][g(16)][s(4)][w(8)][lane(64)][ga(4)][q(4)]  (16 f16/lane)
// LSTM1/2 layout (round-2): [tc][bq(8)][w(8)][fp(4)][lane(64)][8]
// ---------------------------------------------------------------------------
template <int M>
__device__ __forceinline__ void xg_block(int tc, int bq, int t0,
    const float* __restrict__ x, const _Float16* __restrict__ wihp,
    const float* __restrict__ bias, _Float16* __restrict__ xgp, _Float16* axf)
{
    constexpr int D   = (M == 0) ? 300 : ((M == 1) ? 74 : 35);
    constexpr int KCX = (M == 0) ? 10 : ((M == 1) ? 3 : 2);
    const int t = t0 + tc;
    const int tid = threadIdx.x, w = tid >> 6, l = tid & 63, ccol = l & 15;
    const int r0 = bq * 64;

    // stage A tile (64 rows x KCX*32 k) as f16 frags in LDS
    for (int sI = tid; sI < 4 * KCX * 64; sI += 512) {
        int rt = sI / (KCX * 64);
        int kc = (sI >> 6) % KCX;
        int ll = sI & 63;
        int row = r0 + rt * 16 + (ll & 15);
        int kb = kc * 32 + ((ll >> 4) << 3);
        const float* bp = x + ((size_t)row * 128 + t) * D + kb;
        h8 v;
#pragma unroll
        for (int i = 0; i < 8; i++) v[i] = (_Float16)((kb + i < D) ? bp[i] : 0.f);
        *(h8*)&axf[sI * 8] = v;
    }
    __syncthreads();

    if (M == 0) {
        f4 acc[4][8];
#pragma unroll
        for (int g = 0; g < 8; g++) {
            int gt = (g >> 1) * 16 + 2 * w + (g & 1);
            float b = bias[gt * 16 + ccol];
#pragma unroll
            for (int rt = 0; rt < 4; rt++) acc[rt][g] = (f4){b, b, b, b};
        }
#pragma unroll
        for (int kc = 0; kc < KCX; kc++) {
            h8 a[4];
#pragma unroll
            for (int rt = 0; rt < 4; rt++) a[rt] = *(const h8*)&axf[((rt * KCX + kc) * 64 + l) * 8];
#pragma unroll
            for (int g = 0; g < 8; g++) {
                int gt = (g >> 1) * 16 + 2 * w + (g & 1);
                h8 b = *(const h8*)&wihp[((size_t)(gt * KCX + kc) * 64 + l) * 8];
#pragma unroll
                for (int rt = 0; rt < 4; rt++)
                    acc[rt][g] = __builtin_amdgcn_mfma_f32_16x16x32_f16(a[rt], b, acc[rt][g], 0, 0, 0);
            }
        }
        // store in rec-LSTM0 acc-frag layout; lane' == l, q' == q (derived)
#pragma unroll
        for (int rtw = 0; rtw < 4; rtw++) {
            int gr = bq * 2 + (rtw >> 1), rt = rtw & 1;
#pragma unroll
            for (int gi = 0; gi < 8; gi++) {
                int ga = gi >> 1;
                int e = 2 * w + (gi & 1);
                int s2 = e >> 2;
                int w2 = (e & 3) * 2 + rt;
                f4 a = acc[rtw][gi];
                h4 v;
#pragma unroll
                for (int q = 0; q < 4; q++) v[q] = (_Float16)a[q];
                size_t off = (size_t)tc * 524288 +
                             ((((size_t)gr * 4 + s2) * 8 + w2) * 64 + l) * 16 + ga * 4;
                *(h4*)&xgp[off] = v;
            }
        }
    } else {
        const int rh = w >> 2, ht = w & 3;
        f4 acc[2][4];
#pragma unroll
        for (int ga = 0; ga < 4; ga++) {
            int gt = ga * 4 + ht;
            float b = bias[gt * 16 + ccol];
            acc[0][ga] = (f4){b, b, b, b};
            acc[1][ga] = (f4){b, b, b, b};
        }
#pragma unroll
        for (int kc = 0; kc < KCX; kc++) {
            h8 a[2];
#pragma unroll
            for (int rr = 0; rr < 2; rr++)
                a[rr] = *(const h8*)&axf[(((rh * 2 + rr) * KCX + kc) * 64 + l) * 8];
#pragma unroll
            for (int ga = 0; ga < 4; ga++) {
                int gt = ga * 4 + ht;
                h8 b = *(const h8*)&wihp[((size_t)(gt * KCX + kc) * 64 + l) * 8];
#pragma unroll
                for (int rr = 0; rr < 2; rr++)
                    acc[rr][ga] = __builtin_amdgcn_mfma_f32_16x16x32_f16(a[rr], b, acc[rr][ga], 0, 0, 0);
            }
        }
#pragma unroll
        for (int rr = 0; rr < 2; rr++)
#pragma unroll
        for (int gp = 0; gp < 2; gp++) {
            f4 lo = acc[rr][2 * gp], hi = acc[rr][2 * gp + 1];
            h8 v;
#pragma unroll
            for (int q = 0; q < 4; q++) { v[q] = (_Float16)lo[q]; v[4 + q] = (_Float16)hi[q]; }
            int fp = rr * 2 + gp;
            size_t off = ((((size_t)tc * 8 + bq) * 8 + w) * 4 + fp) * 64 + l;
            *(h8*)&xgp[off * 8] = v;
        }
    }
}

__global__ __launch_bounds__(512, 2) void xg_kernel(
    const float* __restrict__ x0, const float* __restrict__ x1, const float* __restrict__ x2,
    const _Float16* __restrict__ wihp0, const _Float16* __restrict__ wihp1,
    const _Float16* __restrict__ wihp2, const float* __restrict__ biasc,
    _Float16* __restrict__ xgp0, _Float16* __restrict__ xgp1, _Float16* __restrict__ xgp2,
    int t0, int TC)
{
    __shared__ __align__(16) _Float16 axf[4 * 10 * 64 * 8];
    int b = blockIdx.x;
    int per = TC * 8;
    if (b < per)            xg_block<0>(b >> 3, b & 7, t0, x0, wihp0, biasc,        xgp0, axf);
    else if (b < 2 * per) { b -= per;     xg_block<1>(b >> 3, b & 7, t0, x1, wihp1, biasc + 1024, xgp1, axf); }
    else                  { b -= 2 * per; xg_block<2>(b >> 3, b & 7, t0, x2, wihp2, biasc + 1280, xgp2, axf); }
}

// ---------------------------------------------------------------------------
// Recurrence. Grid = 80 blocks x 512 threads.
//   bid 0-63 : LSTM0, gate-split 4-way. g = bid&15 (batch group of 32 rows),
//              s = bid>>4 (64 h-cols). w_hh slice (128KB) LDS-resident.
//              Full h rebuilt per step via hx[t][g] exchange (sc1 + counter).
//   bid 64-71: LSTM1 (64 rows each).  bid 72-79: LSTM2.  (LDS-resident, no sync)
// ---------------------------------------------------------------------------
__global__ __launch_bounds__(512, 1) void rec_kernel(
    const _Float16* __restrict__ whhp0, const _Float16* __restrict__ whhp1,
    const _Float16* __restrict__ whhp2,
    const _Float16* __restrict__ xgp0, const _Float16* __restrict__ xgp1,
    const _Float16* __restrict__ xgp2,
    float* __restrict__ h_all, float* __restrict__ csave, _Float16* __restrict__ hsave,
    u64* __restrict__ hx, int* __restrict__ ctr,
    int t0, int TC)
{
    __shared__ __align__(16) char smem[151552];
    const int bid = blockIdx.x;
    const int tid = threadIdx.x, w = tid >> 6, l = tid & 63;
    const int ccol = l & 15, crow = (l >> 4) * 4;

    if (bid < 64) {
        // ----- LSTM0, slice block -----
        const int g = bid & 15, s = bid >> 4;
        const int r0 = g * 32;
        _Float16* whhs   = (_Float16*)smem;              // [16][8][64][8] = 128KB
        _Float16* apack  = (_Float16*)(smem + 131072);   // [kc8][rt2][64][8] = 16KB
        _Float16* hstage = (_Float16*)(smem + 147456);   // own slice frag image, 4KB
        const int hgroup = w >> 1, rt = w & 1;

        // w_hh slice -> LDS (gt' = ga*4+hgroup  <->  global gt = ga*16 + s*4 + hgroup)
        for (int v = tid; v < 8192; v += 512) {
            int gtl = v >> 9, off = v & 511;
            int gt = (gtl >> 2) * 16 + s * 4 + (gtl & 3);
            ((u32x4*)whhs)[v] = ((const u32x4*)whhp0)[(size_t)gt * 512 + off];
        }
        float c[4];
        float* cs = csave + ((size_t)bid * 512 + tid) * 4;
        if (t0 == 0) {
#pragma unroll
            for (int i = 0; i < 4; i++) c[i] = 0.f;
            u32x4 z = (u32x4){0u, 0u, 0u, 0u};
            for (int v = tid; v < 1024; v += 512) ((u32x4*)apack)[v] = z;
        } else {
#pragma unroll
            for (int i = 0; i < 4; i++) c[i] = cs[i];
            for (int v = tid; v < 2048; v += 512)
                ((u64*)apack)[v] = __hip_atomic_load(&hx[((size_t)(t0 - 1) * 16 + g) * 2048 + v],
                                                     __ATOMIC_RELAXED, __HIP_MEMORY_SCOPE_AGENT);
        }
        __syncthreads();

        const _Float16* xgb = xgp0 + ((((size_t)g * 4 + s) * 8 + w) * 64 + l) * 16;
        h8 xcur0 = *(const h8*)&xgb[0];
        h8 xcur1 = *(const h8*)&xgb[8];

        f4 acc[4];
        for (int tc = 0; tc < TC; tc++) {
            const int t = t0 + tc;
            // acc init from xg (bias folded)
#pragma unroll
            for (int q = 0; q < 4; q++) {
                acc[0][q] = (float)xcur0[q];
                acc[1][q] = (float)xcur0[4 + q];
                acc[2][q] = (float)xcur1[q];
                acc[3][q] = (float)xcur1[4 + q];
            }
            // prefetch next xg (covered by MFMA + update)
            h8 xn0 = xcur0, xn1 = xcur1;
            if (tc + 1 < TC) {
                xn0 = *(const h8*)&xgb[(size_t)(tc + 1) * 524288];
                xn1 = *(const h8*)&xgb[(size_t)(tc + 1) * 524288 + 8];
            }
            // gates += h @ w_hh_slice^T
#pragma unroll
            for (int kc = 0; kc < 8; kc++) {
                h8 a = *(const h8*)&apack[((kc * 2 + rt) * 64 + l) * 8];
#pragma unroll
                for (int ga = 0; ga < 4; ga++) {
                    h8 b = *(const h8*)&whhs[(((ga * 4 + hgroup) * 8 + kc) * 64 + l) * 8];
                    acc[ga] = __builtin_amdgcn_mfma_f32_16x16x32_f16(a, b, acc[ga], 0, 0, 0);
                }
            }
            // cell update (all 4 gates in-register)
#pragma unroll
            for (int q = 0; q < 4; q++) {
                float gi = acc[0][q], gf = acc[1][q], gg = acc[2][q], go = acc[3][q];
                float cn = sigm(gf) * c[q] + sigm(gi) * tanhf_(gg);
                c[q] = cn;
                float hv = sigm(go) * tanhf_(cn);
                int row = rt * 16 + crow + q;
                int hcol = hgroup * 16 + ccol;
                if (t == 127) {
                    h_all[(size_t)(r0 + row) * 384 + s * 64 + hcol] = hv;
                } else {
                    int lane2 = (((hcol & 31) >> 3) << 4) | (row & 15);
                    hstage[(((hcol >> 5) * 2 + rt) * 64 + lane2) * 8 + (l & 7)] = (_Float16)hv;
                }
            }
            xcur0 = xn0; xcur1 = xn1;
            __syncthreads();   // hstage complete; all apack reads done; vmcnt drained
            if (t < 127) {
                // publish own slice (4KB) device-visible
                u64 hval = ((u64*)hstage)[tid];
                __hip_atomic_store(&hx[(((size_t)t * 16 + g) * 4 + s) * 512 + tid], hval,
                                   __ATOMIC_RELAXED, __HIP_MEMORY_SCOPE_AGENT);
                __syncthreads();   // drains vmcnt(0): all sc1 stores globally visible
                if (tid == 0) {
                    int old = __hip_atomic_fetch_add(&ctr[t * 16 + g], 1,
                                                     __ATOMIC_RELAXED, __HIP_MEMORY_SCOPE_AGENT);
                    if (old < 3)
                        while (__hip_atomic_load(&ctr[t * 16 + g],
                                                 __ATOMIC_RELAXED, __HIP_MEMORY_SCOPE_AGENT) < 4) {}
                }
                __syncthreads();
                // gather full h(t+1) -> apack
                for (int v = tid; v < 2048; v += 512)
                    ((u64*)apack)[v] = __hip_atomic_load(&hx[((size_t)t * 16 + g) * 2048 + v],
                                                         __ATOMIC_RELAXED, __HIP_MEMORY_SCOPE_AGENT);
                __syncthreads();
            }
        }
        if (t0 + TC < 128) {
#pragma unroll
            for (int i = 0; i < 4; i++) cs[i] = c[i];
        }
    } else {
        // ----- LSTM1 / LSTM2 (round-2 structure, LDS-resident) -----
        const int m = (bid < 72) ? 1 : 2;
        const int lb = (bid - 64) & 7;
        const int r0 = lb * 64;
        const int colb = (m == 1) ? 256 : 320;
        const _Float16* whhp = (m == 1) ? whhp1 : whhp2;
        const _Float16* xgp  = (m == 1) ? xgp1 : xgp2;
        _Float16* whhs = (_Float16*)smem;                 // 32 KB
        _Float16* apkA = (_Float16*)(smem + 32768);       // 8 KB
        _Float16* apkB = (_Float16*)(smem + 40960);       // 8 KB
        const int rh = w >> 2, ht = w & 3;
        float c[8];
        h8 xbuf[4];
        float* cs = csave + 131072 + (((size_t)(bid - 64)) * 512 + tid) * 8;
        for (int v = tid; v < 2048; v += 512) ((u32x4*)whhs)[v] = ((const u32x4*)whhp)[v];
        if (t0 == 0) {
#pragma unroll
            for (int i = 0; i < 8; i++) c[i] = 0.f;
            u32x4 z = (u32x4){0u, 0u, 0u, 0u};
            for (int v = tid; v < 512; v += 512) ((u32x4*)apkA)[v] = z;
        } else {
#pragma unroll
            for (int i = 0; i < 8; i++) c[i] = cs[i];
            const u32x4* hsrc = (const u32x4*)(hsave + (size_t)(bid - 64) * 4096);
            for (int v = tid; v < 512; v += 512) ((u32x4*)apkA)[v] = hsrc[v];
        }
        __syncthreads();

        const size_t xbase = ((size_t)lb * 8 + w) * 4 * 512 + (size_t)l * 8;
#pragma unroll
        for (int fp = 0; fp < 4; fp++)
            xbuf[fp] = *(const h8*)&xgp[xbase + (size_t)fp * 512];

        f4 acc[2][4];
        for (int tc = 0; tc < TC; tc++) {
            _Float16* cur = (tc & 1) ? apkB : apkA;
            _Float16* nxt = (tc & 1) ? apkA : apkB;
#pragma unroll
            for (int rr = 0; rr < 2; rr++)
#pragma unroll
            for (int gp = 0; gp < 2; gp++) {
                int fp = rr * 2 + gp;
#pragma unroll
                for (int q = 0; q < 4; q++) {
                    acc[rr][2 * gp][q]     = (float)xbuf[fp][q];
                    acc[rr][2 * gp + 1][q] = (float)xbuf[fp][4 + q];
                }
            }
            if (tc + 1 < TC) {
                size_t nb = xbase + (size_t)(tc + 1) * 8 * 8 * 4 * 512;
#pragma unroll
                for (int fp = 0; fp < 4; fp++)
                    xbuf[fp] = *(const h8*)&xgp[nb + (size_t)fp * 512];
            }
#pragma unroll
            for (int kc = 0; kc < 2; kc++) {
                h8 a0 = *(const h8*)&cur[(((rh * 2 + 0) * 2 + kc) * 64 + l) * 8];
                h8 a1 = *(const h8*)&cur[(((rh * 2 + 1) * 2 + kc) * 64 + l) * 8];
#pragma unroll
                for (int ga = 0; ga < 4; ga++) {
                    int gt = ga * 4 + ht;
                    h8 b = *(const h8*)&whhs[((gt * 2 + kc) * 64 + l) * 8];
                    acc[0][ga] = __builtin_amdgcn_mfma_f32_16x16x32_f16(a0, b, acc[0][ga], 0, 0, 0);
                    acc[1][ga] = __builtin_amdgcn_mfma_f32_16x16x32_f16(a1, b, acc[1][ga], 0, 0, 0);
                }
            }
            const int t = t0 + tc;
#pragma unroll
            for (int rr = 0; rr < 2; rr++)
#pragma unroll
            for (int q = 0; q < 4; q++) {
                int idx = rr * 4 + q;
                float gi = acc[rr][0][q];
                float gf = acc[rr][1][q];
                float gg = acc[rr][2][q];
                float go = acc[rr][3][q];
                float cn = sigm(gf) * c[idx] + sigm(gi) * tanhf_(gg);
                c[idx] = cn;
                float hv = sigm(go) * tanhf_(cn);
                int row = (rh * 2 + rr) * 16 + crow + q;
                int hcol = ht * 16 + ccol;
                if (t == 127) h_all[(size_t)(r0 + row) * 384 + colb + hcol] = hv;
                int kch = ht >> 1;
                int sub = (ht & 1) * 2 + (ccol >> 3);
                nxt[(((row >> 4) * 2 + kch) * 64 + sub * 16 + (row & 15)) * 8 + (ccol & 7)] = (_Float16)hv;
            }
            __syncthreads();
        }
        if (t0 + TC < 128) {
#pragma unroll
            for (int i = 0; i < 8; i++) cs[i] = c[i];
            u32x4* hdst = (u32x4*)(hsave + (size_t)(bid - 64) * 4096);
            const u32x4* src = (const u32x4*)((TC & 1) ? apkB : apkA);
            for (int v = tid; v < 512; v += 512) hdst[v] = src[v];
        }
    }
}

// ---------------------------------------------------------------------------
// MLP head (unchanged — verified)
// ---------------------------------------------------------------------------
__global__ __launch_bounds__(512) void mlp_kernel(const float* __restrict__ h_all,
                                                  const float* __restrict__ w1,
                                                  const float* __restrict__ b1,
                                                  const float* __restrict__ w2,
                                                  const float* __restrict__ b2,
                                                  float* __restrict__ out)
{
    __shared__ float w1s[64 * 385];
    __shared__ float hs[8 * 384];
    int tid = threadIdx.x;
    for (int idx = tid; idx < 64 * 384; idx += 512) {
        int j = idx / 384, k = idx - j * 384;
        w1s[j * 385 + k] = w1[idx];
    }
    int r0 = blockIdx.x * 8;
    for (int idx = tid; idx < 8 * 384; idx += 512) hs[idx] = h_all[(size_t)r0 * 384 + idx];
    __syncthreads();

    int w = tid >> 6, j = tid & 63;
    float accv = b1[j];
    const float* hrow = &hs[w * 384];
    for (int k = 0; k < 384; k++) accv = fmaf(hrow[k], w1s[j * 385 + k], accv);
    float hid = fmaxf(accv, 0.f);
    float v = hid * w2[j];
#pragma unroll
    for (int off = 32; off >= 1; off >>= 1) v += __shfl_xor(v, off, 64);
    if (j == 0) out[r0 + w] = v + b2[0];
}

// ---------------------------------------------------------------------------
extern "C" void kernel_launch(void* const* d_in, const int* in_sizes, int n_in,
                              void* d_out, int out_size, void* d_ws, size_t ws_size,
                              hipStream_t stream)
{
    const float* x0   = (const float*)d_in[0];
    const float* x1   = (const float*)d_in[1];
    const float* x2   = (const float*)d_in[2];
    const float* wih0 = (const float*)d_in[3];
    const float* whh0 = (const float*)d_in[4];
    const float* bih0 = (const float*)d_in[5];
    const float* bhh0 = (const float*)d_in[6];
    const float* wih1 = (const float*)d_in[7];
    const float* whh1 = (const float*)d_in[8];
    const float* bih1 = (const float*)d_in[9];
    const float* bhh1 = (const float*)d_in[10];
    const float* wih2 = (const float*)d_in[11];
    const float* whh2 = (const float*)d_in[12];
    const float* bih2 = (const float*)d_in[13];
    const float* bhh2 = (const float*)d_in[14];
    const float* w1   = (const float*)d_in[15];
    const float* b1   = (const float*)d_in[16];
    const float* w2   = (const float*)d_in[17];
    const float* b2   = (const float*)d_in[18];

    char* ws = (char*)d_ws;
    size_t off = 0;
    auto alloc = [&](size_t bytes) { size_t o = off; off = (off + bytes + 255) & ~255ULL; return o; };
    size_t o_wihp0 = alloc(655360);
    size_t o_whhp0 = alloc(524288);
    size_t o_wihp1 = alloc(49152);
    size_t o_whhp1 = alloc(32768);
    size_t o_wihp2 = alloc(32768);
    size_t o_whhp2 = alloc(32768);
    size_t o_bias  = alloc(6144);
    size_t o_hall  = alloc(786432);
    size_t o_csave = alloc(786432);
    size_t o_hsave = alloc(131072);
    size_t o_hx    = alloc(33554432);   // hx[128][16][2048] u64 (16KB per (t,g))
    size_t o_ctr   = alloc(8192);       // ctr[128][16]
    size_t fixed = off;

    int TC = 128;
    while (TC > 1 && fixed + (size_t)TC * 1572864ULL + 1024 > ws_size) TC >>= 1;
    size_t o_xgp0 = alloc((size_t)TC * 1048576ULL);
    size_t o_xgp1 = alloc((size_t)TC * 262144ULL);
    size_t o_xgp2 = alloc((size_t)TC * 262144ULL);

    _Float16* wihp0 = (_Float16*)(ws + o_wihp0);
    _Float16* whhp0 = (_Float16*)(ws + o_whhp0);
    _Float16* wihp1 = (_Float16*)(ws + o_wihp1);
    _Float16* whhp1 = (_Float16*)(ws + o_whhp1);
    _Float16* wihp2 = (_Float16*)(ws + o_wihp2);
    _Float16* whhp2 = (_Float16*)(ws + o_whhp2);
    float*    biasc = (float*)(ws + o_bias);
    float*    hall  = (float*)(ws + o_hall);
    float*    csave = (float*)(ws + o_csave);
    _Float16* hsave = (_Float16*)(ws + o_hsave);
    u64*      hx    = (u64*)(ws + o_hx);
    int*      ctr   = (int*)(ws + o_ctr);
    _Float16* xgp0  = (_Float16*)(ws + o_xgp0);
    _Float16* xgp1  = (_Float16*)(ws + o_xgp1);
    _Float16* xgp2  = (_Float16*)(ws + o_xgp2);

    hipMemsetAsync(ws + o_ctr, 0, 8192, stream);

    pack_all<<<330, 256, 0, stream>>>(wih0, whh0, wih1, whh1, wih2, whh2,
                                      bih0, bhh0, bih1, bhh1, bih2, bhh2,
                                      wihp0, whhp0, wihp1, whhp1, wihp2, whhp2, biasc);

    for (int t0 = 0; t0 < 128; t0 += TC) {
        xg_kernel<<<24 * TC, 512, 0, stream>>>(x0, x1, x2, wihp0, wihp1, wihp2, biasc,
                                               xgp0, xgp1, xgp2, t0, TC);
        rec_kernel<<<80, 512, 0, stream>>>(whhp0, whhp1, whhp2, xgp0, xgp1, xgp2,
                                           hall, csave, hsave, hx, ctr, t0, TC);
    }

    mlp_kernel<<<64, 512, 0, stream>>>(hall, w1, b1, w2, b2, (float*)d_out);
}

// Round 4
// 571.207 us; speedup vs baseline: 6.2752x; 1.1293x over previous
//
#include <hip/hip_runtime.h>

typedef _Float16 h8 __attribute__((ext_vector_type(8)));
typedef _Float16 h4 __attribute__((ext_vector_type(4)));
typedef float f4 __attribute__((ext_vector_type(4)));
typedef unsigned int u32x4 __attribute__((ext_vector_type(4)));
typedef unsigned long long u64;
typedef unsigned int u32;

__device__ __forceinline__ float sigm(float x) { return 1.f / (1.f + __expf(-x)); }
__device__ __forceinline__ float tanhf_(float x) { return 1.f - 2.f / (1.f + __expf(2.f * x)); }

// ---------------------------------------------------------------------------
// pack_all: weights -> f16 fragment layout [gt][kc][lane][8],
// value(gt,kc,lane,i) = W[gt*16 + (lane&15)][kc*32 + ((lane>>4)<<3) + i] (0-pad).
// biasc = b_ih + b_hh (f32).
// ---------------------------------------------------------------------------
__global__ __launch_bounds__(256) void pack_all(
    const float* __restrict__ wih0, const float* __restrict__ whh0,
    const float* __restrict__ wih1, const float* __restrict__ whh1,
    const float* __restrict__ wih2, const float* __restrict__ whh2,
    const float* __restrict__ bih0, const float* __restrict__ bhh0,
    const float* __restrict__ bih1, const float* __restrict__ bhh1,
    const float* __restrict__ bih2, const float* __restrict__ bhh2,
    _Float16* __restrict__ wihp0, _Float16* __restrict__ whhp0,
    _Float16* __restrict__ wihp1, _Float16* __restrict__ whhp1,
    _Float16* __restrict__ wihp2, _Float16* __restrict__ whhp2,
    float* __restrict__ biasc)
{
    if (blockIdx.x >= 324) {
        int bi = (blockIdx.x - 324) * 256 + threadIdx.x;
        if (bi < 1024)      biasc[bi] = bih0[bi] + bhh0[bi];
        else if (bi < 1280) biasc[bi] = bih1[bi - 1024] + bhh1[bi - 1024];
        else if (bi < 1536) biasc[bi] = bih2[bi - 1280] + bhh2[bi - 1280];
        return;
    }
    int s = blockIdx.x * 256 + threadIdx.x;
    const float* src; _Float16* dst; int KC, D;
    if (s < 40960)      {            dst = wihp0; src = wih0; KC = 10; D = 300; }
    else if (s < 73728) { s -= 40960; dst = whhp0; src = whh0; KC = 8;  D = 256; }
    else if (s < 76800) { s -= 73728; dst = wihp1; src = wih1; KC = 3;  D = 74;  }
    else if (s < 78848) { s -= 76800; dst = whhp1; src = whh1; KC = 2;  D = 64;  }
    else if (s < 80896) { s -= 78848; dst = wihp2; src = wih2; KC = 2;  D = 35;  }
    else                { s -= 80896; dst = whhp2; src = whh2; KC = 2;  D = 64;  }
    int lane = s & 63;
    int kc = (s >> 6) % KC;
    int gt = (s >> 6) / KC;
    int g = gt * 16 + (lane & 15);
    int kb = kc * 32 + ((lane >> 4) << 3);
    h8 v;
#pragma unroll
    for (int i = 0; i < 8; i++) {
        int k = kb + i;
        v[i] = (_Float16)((k < D) ? src[(size_t)g * D + k] : 0.f);
    }
    *(h8*)&dst[(size_t)s * 8] = v;
}

// ---------------------------------------------------------------------------
// xg phase: xg = x @ w_ih^T + bias (f16), pre-packed for the recurrence.
// LSTM0 layout: [tc][g(16)][s(4)][w(8)][lane(64)][ga(4)][q(4)]  (16 f16/lane)
// LSTM1/2 layout: [tc][bq(8)][w(8)][fp(4)][lane(64)][8]
// ---------------------------------------------------------------------------
template <int M>
__device__ __forceinline__ void xg_block(int tc, int bq, int t0,
    const float* __restrict__ x, const _Float16* __restrict__ wihp,
    const float* __restrict__ bias, _Float16* __restrict__ xgp, _Float16* axf)
{
    constexpr int D   = (M == 0) ? 300 : ((M == 1) ? 74 : 35);
    constexpr int KCX = (M == 0) ? 10 : ((M == 1) ? 3 : 2);
    const int t = t0 + tc;
    const int tid = threadIdx.x, w = tid >> 6, l = tid & 63, ccol = l & 15;
    const int r0 = bq * 64;

    // stage A tile (64 rows x KCX*32 k) as f16 frags in LDS
    for (int sI = tid; sI < 4 * KCX * 64; sI += 512) {
        int rt = sI / (KCX * 64);
        int kc = (sI >> 6) % KCX;
        int ll = sI & 63;
        int row = r0 + rt * 16 + (ll & 15);
        int kb = kc * 32 + ((ll >> 4) << 3);
        const float* bp = x + ((size_t)row * 128 + t) * D + kb;
        h8 v;
#pragma unroll
        for (int i = 0; i < 8; i++) v[i] = (_Float16)((kb + i < D) ? bp[i] : 0.f);
        *(h8*)&axf[sI * 8] = v;
    }
    __syncthreads();

    if (M == 0) {
        f4 acc[4][8];
#pragma unroll
        for (int g = 0; g < 8; g++) {
            int gt = (g >> 1) * 16 + 2 * w + (g & 1);
            float b = bias[gt * 16 + ccol];
#pragma unroll
            for (int rt = 0; rt < 4; rt++) acc[rt][g] = (f4){b, b, b, b};
        }
#pragma unroll
        for (int kc = 0; kc < KCX; kc++) {
            h8 a[4];
#pragma unroll
            for (int rt = 0; rt < 4; rt++) a[rt] = *(const h8*)&axf[((rt * KCX + kc) * 64 + l) * 8];
#pragma unroll
            for (int g = 0; g < 8; g++) {
                int gt = (g >> 1) * 16 + 2 * w + (g & 1);
                h8 b = *(const h8*)&wihp[((size_t)(gt * KCX + kc) * 64 + l) * 8];
#pragma unroll
                for (int rt = 0; rt < 4; rt++)
                    acc[rt][g] = __builtin_amdgcn_mfma_f32_16x16x32_f16(a[rt], b, acc[rt][g], 0, 0, 0);
            }
        }
        // store in rec-LSTM0 acc-frag layout
#pragma unroll
        for (int rtw = 0; rtw < 4; rtw++) {
            int gr = bq * 2 + (rtw >> 1), rt = rtw & 1;
#pragma unroll
            for (int gi = 0; gi < 8; gi++) {
                int ga = gi >> 1;
                int e = 2 * w + (gi & 1);
                int s2 = e >> 2;
                int w2 = (e & 3) * 2 + rt;
                f4 a = acc[rtw][gi];
                h4 v;
#pragma unroll
                for (int q = 0; q < 4; q++) v[q] = (_Float16)a[q];
                size_t off = (size_t)tc * 524288 +
                             ((((size_t)gr * 4 + s2) * 8 + w2) * 64 + l) * 16 + ga * 4;
                *(h4*)&xgp[off] = v;
            }
        }
    } else {
        const int rh = w >> 2, ht = w & 3;
        f4 acc[2][4];
#pragma unroll
        for (int ga = 0; ga < 4; ga++) {
            int gt = ga * 4 + ht;
            float b = bias[gt * 16 + ccol];
            acc[0][ga] = (f4){b, b, b, b};
            acc[1][ga] = (f4){b, b, b, b};
        }
#pragma unroll
        for (int kc = 0; kc < KCX; kc++) {
            h8 a[2];
#pragma unroll
            for (int rr = 0; rr < 2; rr++)
                a[rr] = *(const h8*)&axf[(((rh * 2 + rr) * KCX + kc) * 64 + l) * 8];
#pragma unroll
            for (int ga = 0; ga < 4; ga++) {
                int gt = ga * 4 + ht;
                h8 b = *(const h8*)&wihp[((size_t)(gt * KCX + kc) * 64 + l) * 8];
#pragma unroll
                for (int rr = 0; rr < 2; rr++)
                    acc[rr][ga] = __builtin_amdgcn_mfma_f32_16x16x32_f16(a[rr], b, acc[rr][ga], 0, 0, 0);
            }
        }
#pragma unroll
        for (int rr = 0; rr < 2; rr++)
#pragma unroll
        for (int gp = 0; gp < 2; gp++) {
            f4 lo = acc[rr][2 * gp], hi = acc[rr][2 * gp + 1];
            h8 v;
#pragma unroll
            for (int q = 0; q < 4; q++) { v[q] = (_Float16)lo[q]; v[4 + q] = (_Float16)hi[q]; }
            int fp = rr * 2 + gp;
            size_t off = ((((size_t)tc * 8 + bq) * 8 + w) * 4 + fp) * 64 + l;
            *(h8*)&xgp[off * 8] = v;
        }
    }
}

__global__ __launch_bounds__(512, 2) void xg_kernel(
    const float* __restrict__ x0, const float* __restrict__ x1, const float* __restrict__ x2,
    const _Float16* __restrict__ wihp0, const _Float16* __restrict__ wihp1,
    const _Float16* __restrict__ wihp2, const float* __restrict__ biasc,
    _Float16* __restrict__ xgp0, _Float16* __restrict__ xgp1, _Float16* __restrict__ xgp2,
    int t0, int TC)
{
    __shared__ __align__(16) _Float16 axf[4 * 10 * 64 * 8];
    int b = blockIdx.x;
    int per = TC * 8;
    if (b < per)            xg_block<0>(b >> 3, b & 7, t0, x0, wihp0, biasc,        xgp0, axf);
    else if (b < 2 * per) { b -= per;     xg_block<1>(b >> 3, b & 7, t0, x1, wihp1, biasc + 1024, xgp1, axf); }
    else                  { b -= 2 * per; xg_block<2>(b >> 3, b & 7, t0, x2, wihp2, biasc + 1280, xgp2, axf); }
}

// ---------------------------------------------------------------------------
// Recurrence. Grid = 80 blocks x 512 threads.
//   bid 0-63 : LSTM0, gate-split 4-way. g = bid&15 (32-row batch group),
//              s = bid>>4 (64 h-col slice). w_hh slice (128KB) LDS-resident.
//              Exchange per step: publish own 4KB slice -> flag -> per-wave
//              poll of 3 peer flags -> gather 12KB. No RMW anywhere.
//   bid 64-71: LSTM1.  bid 72-79: LSTM2.  (fully LDS-resident, no exchange)
// ---------------------------------------------------------------------------
__global__ __launch_bounds__(512, 1) void rec_kernel(
    const _Float16* __restrict__ whhp0, const _Float16* __restrict__ whhp1,
    const _Float16* __restrict__ whhp2,
    const _Float16* __restrict__ xgp0, const _Float16* __restrict__ xgp1,
    const _Float16* __restrict__ xgp2,
    float* __restrict__ h_all, float* __restrict__ csave, _Float16* __restrict__ hsave,
    u64* __restrict__ hx, u32* __restrict__ flags,
    int t0, int TC)
{
    __shared__ __align__(16) char smem[151552];
    const int bid = blockIdx.x;
    const int tid = threadIdx.x, w = tid >> 6, l = tid & 63;
    const int ccol = l & 15, crow = (l >> 4) * 4;

    if (bid < 64) {
        // ----- LSTM0, slice block -----
        const int g = bid & 15, s = bid >> 4;
        const int r0 = g * 32;
        _Float16* whhs   = (_Float16*)smem;              // [16][8][64][8] = 128KB
        _Float16* apack  = (_Float16*)(smem + 131072);   // [kc8][rt2][64][8] = 16KB
        _Float16* hstage = (_Float16*)(smem + 147456);   // own slice frag image, 4KB
        u64* apack_u64   = (u64*)apack;
        const int hgroup = w >> 1, rt = w & 1;
        const int s1 = (s + 1) & 3, s2 = (s + 2) & 3, s3 = (s + 3) & 3;

        // w_hh slice -> LDS (gt' = ga*4+hgroup  <->  global gt = ga*16 + s*4 + hgroup)
        for (int v = tid; v < 8192; v += 512) {
            int gtl = v >> 9, off = v & 511;
            int gt = (gtl >> 2) * 16 + s * 4 + (gtl & 3);
            ((u32x4*)whhs)[v] = ((const u32x4*)whhp0)[(size_t)gt * 512 + off];
        }
        float c[4];
        float* cs = csave + ((size_t)bid * 512 + tid) * 4;
        if (t0 == 0) {
#pragma unroll
            for (int i = 0; i < 4; i++) c[i] = 0.f;
            u32x4 z = (u32x4){0u, 0u, 0u, 0u};
            for (int v = tid; v < 1024; v += 512) ((u32x4*)apack)[v] = z;
        } else {
#pragma unroll
            for (int i = 0; i < 4; i++) c[i] = cs[i];
            for (int v = tid; v < 2048; v += 512)
                apack_u64[v] = __hip_atomic_load(&hx[((size_t)(t0 - 1) * 16 + g) * 2048 + v],
                                                 __ATOMIC_RELAXED, __HIP_MEMORY_SCOPE_AGENT);
        }
        __syncthreads();

        const _Float16* xgb = xgp0 + ((((size_t)g * 4 + s) * 8 + w) * 64 + l) * 16;
        h8 xcur0 = *(const h8*)&xgb[0];
        h8 xcur1 = *(const h8*)&xgb[8];

        f4 acc[4];
        for (int tc = 0; tc < TC; tc++) {
            const int t = t0 + tc;
            // acc init from xg (bias folded)
#pragma unroll
            for (int q = 0; q < 4; q++) {
                acc[0][q] = (float)xcur0[q];
                acc[1][q] = (float)xcur0[4 + q];
                acc[2][q] = (float)xcur1[q];
                acc[3][q] = (float)xcur1[4 + q];
            }
            // prefetch next xg (covered by MFMA + update)
            h8 xn0 = xcur0, xn1 = xcur1;
            if (tc + 1 < TC) {
                xn0 = *(const h8*)&xgb[(size_t)(tc + 1) * 524288];
                xn1 = *(const h8*)&xgb[(size_t)(tc + 1) * 524288 + 8];
            }
            // gates += h @ w_hh_slice^T
#pragma unroll
            for (int kc = 0; kc < 8; kc++) {
                h8 a = *(const h8*)&apack[((kc * 2 + rt) * 64 + l) * 8];
#pragma unroll
                for (int ga = 0; ga < 4; ga++) {
                    h8 b = *(const h8*)&whhs[(((ga * 4 + hgroup) * 8 + kc) * 64 + l) * 8];
                    acc[ga] = __builtin_amdgcn_mfma_f32_16x16x32_f16(a, b, acc[ga], 0, 0, 0);
                }
            }
            // cell update (all 4 gates in-register)
#pragma unroll
            for (int q = 0; q < 4; q++) {
                float gi = acc[0][q], gf = acc[1][q], gg = acc[2][q], go = acc[3][q];
                float cn = sigm(gf) * c[q] + sigm(gi) * tanhf_(gg);
                c[q] = cn;
                float hv = sigm(go) * tanhf_(cn);
                int row = rt * 16 + crow + q;
                int hcol = hgroup * 16 + ccol;
                if (t == 127) {
                    h_all[(size_t)(r0 + row) * 384 + s * 64 + hcol] = hv;
                } else {
                    int lane2 = (((hcol & 31) >> 3) << 4) | (row & 15);
                    hstage[(((hcol >> 5) * 2 + rt) * 64 + lane2) * 8 + (l & 7)] = (_Float16)hv;
                }
            }
            xcur0 = xn0; xcur1 = xn1;
            __syncthreads();   // B1: hstage complete; all apack MFMA reads done
            if (t < 127) {
                // publish own 4KB slice + copy into own apack region (LDS)
                u64 hval = ((u64*)hstage)[tid];
                __hip_atomic_store(&hx[(((size_t)t * 16 + g) * 4 + s) * 512 + tid], hval,
                                   __ATOMIC_RELAXED, __HIP_MEMORY_SCOPE_AGENT);
                apack_u64[s * 512 + tid] = hval;
                __syncthreads();   // B2: all waves' publish stores complete (vmcnt drained)
                if (tid == 0)
                    __hip_atomic_store(&flags[((size_t)t * 16 + g) * 32 + s], 1u,
                                       __ATOMIC_RELAXED, __HIP_MEMORY_SCOPE_AGENT);
                // per-wave poll of 3 peer flags (uniform addresses across lanes)
                const u32* fl = &flags[((size_t)t * 16 + g) * 32];
                while (true) {
                    u32 fa = __hip_atomic_load(&fl[s1], __ATOMIC_RELAXED, __HIP_MEMORY_SCOPE_AGENT);
                    u32 fb = __hip_atomic_load(&fl[s2], __ATOMIC_RELAXED, __HIP_MEMORY_SCOPE_AGENT);
                    u32 fc = __hip_atomic_load(&fl[s3], __ATOMIC_RELAXED, __HIP_MEMORY_SCOPE_AGENT);
                    if (fa + fb + fc == 3u) break;
                }
                // gather 3 peer slices (12KB) -> apack
                const u64* hxs = &hx[(((size_t)t * 16 + g) * 4) * 512];
                u64 v1 = __hip_atomic_load(&hxs[s1 * 512 + tid], __ATOMIC_RELAXED, __HIP_MEMORY_SCOPE_AGENT);
                u64 v2 = __hip_atomic_load(&hxs[s2 * 512 + tid], __ATOMIC_RELAXED, __HIP_MEMORY_SCOPE_AGENT);
                u64 v3 = __hip_atomic_load(&hxs[s3 * 512 + tid], __ATOMIC_RELAXED, __HIP_MEMORY_SCOPE_AGENT);
                apack_u64[s1 * 512 + tid] = v1;
                apack_u64[s2 * 512 + tid] = v2;
                apack_u64[s3 * 512 + tid] = v3;
                __syncthreads();   // B3: apack = full h(t) ready
            }
        }
        if (t0 + TC < 128) {
#pragma unroll
            for (int i = 0; i < 4; i++) cs[i] = c[i];
        }
    } else {
        // ----- LSTM1 / LSTM2 (LDS-resident, no exchange) -----
        const int m = (bid < 72) ? 1 : 2;
        const int lb = (bid - 64) & 7;
        const int r0 = lb * 64;
        const int colb = (m == 1) ? 256 : 320;
        const _Float16* whhp = (m == 1) ? whhp1 : whhp2;
        const _Float16* xgp  = (m == 1) ? xgp1 : xgp2;
        _Float16* whhs = (_Float16*)smem;                 // 32 KB
        _Float16* apkA = (_Float16*)(smem + 32768);       // 8 KB
        _Float16* apkB = (_Float16*)(smem + 40960);       // 8 KB
        const int rh = w >> 2, ht = w & 3;
        float c[8];
        h8 xbuf[4];
        float* cs = csave + 131072 + (((size_t)(bid - 64)) * 512 + tid) * 8;
        for (int v = tid; v < 2048; v += 512) ((u32x4*)whhs)[v] = ((const u32x4*)whhp)[v];
        if (t0 == 0) {
#pragma unroll
            for (int i = 0; i < 8; i++) c[i] = 0.f;
            u32x4 z = (u32x4){0u, 0u, 0u, 0u};
            for (int v = tid; v < 512; v += 512) ((u32x4*)apkA)[v] = z;
        } else {
#pragma unroll
            for (int i = 0; i < 8; i++) c[i] = cs[i];
            const u32x4* hsrc = (const u32x4*)(hsave + (size_t)(bid - 64) * 4096);
            for (int v = tid; v < 512; v += 512) ((u32x4*)apkA)[v] = hsrc[v];
        }
        __syncthreads();

        const size_t xbase = ((size_t)lb * 8 + w) * 4 * 512 + (size_t)l * 8;
#pragma unroll
        for (int fp = 0; fp < 4; fp++)
            xbuf[fp] = *(const h8*)&xgp[xbase + (size_t)fp * 512];

        f4 acc[2][4];
        for (int tc = 0; tc < TC; tc++) {
            _Float16* cur = (tc & 1) ? apkB : apkA;
            _Float16* nxt = (tc & 1) ? apkA : apkB;
#pragma unroll
            for (int rr = 0; rr < 2; rr++)
#pragma unroll
            for (int gp = 0; gp < 2; gp++) {
                int fp = rr * 2 + gp;
#pragma unroll
                for (int q = 0; q < 4; q++) {
                    acc[rr][2 * gp][q]     = (float)xbuf[fp][q];
                    acc[rr][2 * gp + 1][q] = (float)xbuf[fp][4 + q];
                }
            }
            if (tc + 1 < TC) {
                size_t nb = xbase + (size_t)(tc + 1) * 8 * 8 * 4 * 512;
#pragma unroll
                for (int fp = 0; fp < 4; fp++)
                    xbuf[fp] = *(const h8*)&xgp[nb + (size_t)fp * 512];
            }
#pragma unroll
            for (int kc = 0; kc < 2; kc++) {
                h8 a0 = *(const h8*)&cur[(((rh * 2 + 0) * 2 + kc) * 64 + l) * 8];
                h8 a1 = *(const h8*)&cur[(((rh * 2 + 1) * 2 + kc) * 64 + l) * 8];
#pragma unroll
                for (int ga = 0; ga < 4; ga++) {
                    int gt = ga * 4 + ht;
                    h8 b = *(const h8*)&whhs[((gt * 2 + kc) * 64 + l) * 8];
                    acc[0][ga] = __builtin_amdgcn_mfma_f32_16x16x32_f16(a0, b, acc[0][ga], 0, 0, 0);
                    acc[1][ga] = __builtin_amdgcn_mfma_f32_16x16x32_f16(a1, b, acc[1][ga], 0, 0, 0);
                }
            }
            const int t = t0 + tc;
#pragma unroll
            for (int rr = 0; rr < 2; rr++)
#pragma unroll
            for (int q = 0; q < 4; q++) {
                int idx = rr * 4 + q;
                float gi = acc[rr][0][q];
                float gf = acc[rr][1][q];
                float gg = acc[rr][2][q];
                float go = acc[rr][3][q];
                float cn = sigm(gf) * c[idx] + sigm(gi) * tanhf_(gg);
                c[idx] = cn;
                float hv = sigm(go) * tanhf_(cn);
                int row = (rh * 2 + rr) * 16 + crow + q;
                int hcol = ht * 16 + ccol;
                if (t == 127) h_all[(size_t)(r0 + row) * 384 + colb + hcol] = hv;
                int kch = ht >> 1;
                int sub = (ht & 1) * 2 + (ccol >> 3);
                nxt[(((row >> 4) * 2 + kch) * 64 + sub * 16 + (row & 15)) * 8 + (ccol & 7)] = (_Float16)hv;
            }
            __syncthreads();
        }
        if (t0 + TC < 128) {
#pragma unroll
            for (int i = 0; i < 8; i++) cs[i] = c[i];
            u32x4* hdst = (u32x4*)(hsave + (size_t)(bid - 64) * 4096);
            const u32x4* src = (const u32x4*)((TC & 1) ? apkB : apkA);
            for (int v = tid; v < 512; v += 512) hdst[v] = src[v];
        }
    }
}

// ---------------------------------------------------------------------------
// MLP head (unchanged — verified)
// ---------------------------------------------------------------------------
__global__ __launch_bounds__(512) void mlp_kernel(const float* __restrict__ h_all,
                                                  const float* __restrict__ w1,
                                                  const float* __restrict__ b1,
                                                  const float* __restrict__ w2,
                                                  const float* __restrict__ b2,
                                                  float* __restrict__ out)
{
    __shared__ float w1s[64 * 385];
    __shared__ float hs[8 * 384];
    int tid = threadIdx.x;
    for (int idx = tid; idx < 64 * 384; idx += 512) {
        int j = idx / 384, k = idx - j * 384;
        w1s[j * 385 + k] = w1[idx];
    }
    int r0 = blockIdx.x * 8;
    for (int idx = tid; idx < 8 * 384; idx += 512) hs[idx] = h_all[(size_t)r0 * 384 + idx];
    __syncthreads();

    int w = tid >> 6, j = tid & 63;
    float accv = b1[j];
    const float* hrow = &hs[w * 384];
    for (int k = 0; k < 384; k++) accv = fmaf(hrow[k], w1s[j * 385 + k], accv);
    float hid = fmaxf(accv, 0.f);
    float v = hid * w2[j];
#pragma unroll
    for (int off = 32; off >= 1; off >>= 1) v += __shfl_xor(v, off, 64);
    if (j == 0) out[r0 + w] = v + b2[0];
}

// ---------------------------------------------------------------------------
extern "C" void kernel_launch(void* const* d_in, const int* in_sizes, int n_in,
                              void* d_out, int out_size, void* d_ws, size_t ws_size,
                              hipStream_t stream)
{
    const float* x0   = (const float*)d_in[0];
    const float* x1   = (const float*)d_in[1];
    const float* x2   = (const float*)d_in[2];
    const float* wih0 = (const float*)d_in[3];
    const float* whh0 = (const float*)d_in[4];
    const float* bih0 = (const float*)d_in[5];
    const float* bhh0 = (const float*)d_in[6];
    const float* wih1 = (const float*)d_in[7];
    const float* whh1 = (const float*)d_in[8];
    const float* bih1 = (const float*)d_in[9];
    const float* bhh1 = (const float*)d_in[10];
    const float* wih2 = (const float*)d_in[11];
    const float* whh2 = (const float*)d_in[12];
    const float* bih2 = (const float*)d_in[13];
    const float* bhh2 = (const float*)d_in[14];
    const float* w1   = (const float*)d_in[15];
    const float* b1   = (const float*)d_in[16];
    const float* w2   = (const float*)d_in[17];
    const float* b2   = (const float*)d_in[18];

    char* ws = (char*)d_ws;
    size_t off = 0;
    auto alloc = [&](size_t bytes) { size_t o = off; off = (off + bytes + 255) & ~255ULL; return o; };
    size_t o_wihp0 = alloc(655360);
    size_t o_whhp0 = alloc(524288);
    size_t o_wihp1 = alloc(49152);
    size_t o_whhp1 = alloc(32768);
    size_t o_wihp2 = alloc(32768);
    size_t o_whhp2 = alloc(32768);
    size_t o_bias  = alloc(6144);
    size_t o_hall  = alloc(786432);
    size_t o_csave = alloc(786432);
    size_t o_hsave = alloc(131072);
    size_t o_hx    = alloc(33554432);   // hx[128][16][4][512] u64 (4KB per slice)
    size_t o_flags = alloc(262144);     // flags[128][16][32] u32 (128B per (t,g))
    size_t fixed = off;

    int TC = 128;
    while (TC > 1 && fixed + (size_t)TC * 1572864ULL + 1024 > ws_size) TC >>= 1;
    size_t o_xgp0 = alloc((size_t)TC * 1048576ULL);
    size_t o_xgp1 = alloc((size_t)TC * 262144ULL);
    size_t o_xgp2 = alloc((size_t)TC * 262144ULL);

    _Float16* wihp0 = (_Float16*)(ws + o_wihp0);
    _Float16* whhp0 = (_Float16*)(ws + o_whhp0);
    _Float16* wihp1 = (_Float16*)(ws + o_wihp1);
    _Float16* whhp1 = (_Float16*)(ws + o_whhp1);
    _Float16* wihp2 = (_Float16*)(ws + o_wihp2);
    _Float16* whhp2 = (_Float16*)(ws + o_whhp2);
    float*    biasc = (float*)(ws + o_bias);
    float*    hall  = (float*)(ws + o_hall);
    float*    csave = (float*)(ws + o_csave);
    _Float16* hsave = (_Float16*)(ws + o_hsave);
    u64*      hx    = (u64*)(ws + o_hx);
    u32*      flags = (u32*)(ws + o_flags);
    _Float16* xgp0  = (_Float16*)(ws + o_xgp0);
    _Float16* xgp1  = (_Float16*)(ws + o_xgp1);
    _Float16* xgp2  = (_Float16*)(ws + o_xgp2);

    hipMemsetAsync(ws + o_flags, 0, 262144, stream);

    pack_all<<<330, 256, 0, stream>>>(wih0, whh0, wih1, whh1, wih2, whh2,
                                      bih0, bhh0, bih1, bhh1, bih2, bhh2,
                                      wihp0, whhp0, wihp1, whhp1, wihp2, whhp2, biasc);

    for (int t0 = 0; t0 < 128; t0 += TC) {
        xg_kernel<<<24 * TC, 512, 0, stream>>>(x0, x1, x2, wihp0, wihp1, wihp2, biasc,
                                               xgp0, xgp1, xgp2, t0, TC);
        rec_kernel<<<80, 512, 0, stream>>>(whhp0, whhp1, whhp2, xgp0, xgp1, xgp2,
                                           hall, csave, hsave, hx, flags, t0, TC);
    }

    mlp_kernel<<<64, 512, 0, stream>>>(hall, w1, b1, w2, b2, (float*)d_out);
}